// Round 1
// baseline (286234.668 us; speedup 1.0000x reference)
//
#include <hip/hip_runtime.h>
#include <hip/hip_bf16.h>
#include <math.h>
#include <stdio.h>

#define NWG 128
#define NT  512

#define B_  64
#define T_  128
#define L_  8
#define H_  8
#define D_  512
#define HD_ 64
#define D3_ 1536
#define D4_ 2048

struct P {
  const float *data,*r,*y_d,*wte_w,*wte_b,*wpe,*ln1_w,*ln1_b,*qkv_w,*qkv_b,
              *proj_w,*proj_b,*ln2_w,*ln2_b,*fc_w,*fc_b,*mproj_w,*mproj_b,
              *lnf_w,*lnf_b,*head_w,*head_b;
  float *out, *y, *u, *h, *hn, *o, *hn2, *g;
  __hip_bfloat16 *Kc, *Vc;
  int *sync;
};

// Tree barrier: 4 sub-counters (32 WGs each) -> root(4) -> generation bump.
// Agent-scope acq_rel atomics give the L2 writeback/invalidate needed for
// cross-XCD visibility of plain global stores.
__device__ __forceinline__ void gbar(int* sync, int wg) {
  __syncthreads();
  if (threadIdx.x == 0) {
    unsigned* gen = (unsigned*)(sync + 5*32);
    unsigned g0 = __hip_atomic_load(gen, __ATOMIC_RELAXED, __HIP_MEMORY_SCOPE_AGENT);
    int r = __hip_atomic_fetch_add(sync + (wg>>5)*32, 1, __ATOMIC_ACQ_REL, __HIP_MEMORY_SCOPE_AGENT);
    if (r == 31) {
      __hip_atomic_store(sync + (wg>>5)*32, 0, __ATOMIC_RELAXED, __HIP_MEMORY_SCOPE_AGENT);
      int rr = __hip_atomic_fetch_add(sync + 4*32, 1, __ATOMIC_ACQ_REL, __HIP_MEMORY_SCOPE_AGENT);
      if (rr == 3) {
        __hip_atomic_store(sync + 4*32, 0, __ATOMIC_RELAXED, __HIP_MEMORY_SCOPE_AGENT);
        __hip_atomic_fetch_add(gen, 1u, __ATOMIC_RELEASE, __HIP_MEMORY_SCOPE_AGENT);
      }
    }
    while (__hip_atomic_load(gen, __ATOMIC_RELAXED, __HIP_MEMORY_SCOPE_AGENT) == g0)
      __builtin_amdgcn_s_sleep(2);
    (void)__hip_atomic_load(gen, __ATOMIC_ACQUIRE, __HIP_MEMORY_SCOPE_AGENT);
  }
  __syncthreads();
}

__global__ __launch_bounds__(NT) void gptloop(P p) {
  const int wg  = blockIdx.x;
  const int tid = threadIdx.x;
  __shared__ float red[NT], red2[NT];
  __shared__ float q_sm[2][HD_];
  __shared__ float att_sm[2][T_];

  for (int st = 0; st < T_; ++st) {
    //================= embed + LN1(l=0), WGs 0..63 =================
    if (wg < B_) {
      const int b = wg;
      float y0,y1,u0,u1;
      if (st == 0) { y0=p.y_d[b*256]; y1=p.y_d[b*256+1]; u0=191.713f; u1=215.888f; }
      else { y0=p.y[b*2]; y1=p.y[b*2+1]; u0=p.u[b*2]; u1=p.u[b*2+1]; }
      if (tid == 0) {
        p.out[b*256+st*2]   = y0;
        p.out[b*256+st*2+1] = y1;
        if (st == 0) { p.y[b*2]=y0; p.y[b*2+1]=y1; p.u[b*2]=u0; p.u[b*2+1]=u1; }
      }
      const float e0 = p.r[b*256+st*2]   - y0;
      const float e1 = p.r[b*256+st*2+1] - y1;
      const int d = tid;
      float hv = e0*p.wte_w[d] + e1*p.wte_w[D_+d] + u0*p.wte_w[2*D_+d] + u1*p.wte_w[3*D_+d]
               + p.wte_b[d] + p.wpe[st*D_+d];
      p.h[b*D_+d] = hv;
      red[tid]=hv; red2[tid]=hv*hv; __syncthreads();
      for (int s2=256;s2>=1;s2>>=1){ if(tid<s2){red[tid]+=red[tid+s2];red2[tid]+=red2[tid+s2];} __syncthreads(); }
      const float mu = red[0]*(1.f/D_);
      const float var = red2[0]*(1.f/D_)-mu*mu;
      const float rs = rsqrtf(var+1e-5f);
      p.hn[b*D_+d] = (hv-mu)*rs*p.ln1_w[d] + p.ln1_b[d];
      __syncthreads();
    }
    gbar(p.sync, wg);

    for (int l = 0; l < L_; ++l) {
      //================= qkv + attention (512 (b,h) pairs over 256 virtual WGs) =================
      for (int vv=0; vv<2; ++vv) {
        const int vw = wg + vv*NWG;           // 0..255
        const int half = tid >> 8, j = tid & 255;
        const int pair = vw*2 + half;         // 0..511
        const int b = pair >> 3, hh = pair & 7;
        const size_t kvbase = ((size_t)((l*B_+b)*H_+hh))*(size_t)(T_*HD_);
        if (j < 192) {
          const int part = j>>6, jj = j&63;
          const int col = part*D_ + hh*HD_ + jj;
          const float* wc = p.qkv_w + l*(D_*D3_) + col;
          const float* hr = p.hn + b*D_;
          float acc = p.qkv_b[l*D3_+col];
          #pragma unroll 8
          for (int k=0;k<D_;++k) acc += hr[k]*wc[k*D3_];
          if (part==0)      q_sm[half][jj] = acc*0.125f;               // fold 1/sqrt(HD)
          else if (part==1) p.Kc[kvbase + st*HD_ + jj] = __float2bfloat16(acc);
          else              p.Vc[kvbase + st*HD_ + jj] = __float2bfloat16(acc);
        }
        __syncthreads();
        float s = -1e30f;
        if (j <= st) {
          const __hip_bfloat16* kr = p.Kc + kvbase + (size_t)j*HD_;
          float sc = 0.f;
          #pragma unroll 8
          for (int kk=0;kk<HD_;++kk) sc += q_sm[half][kk]*__bfloat162float(kr[kk]);
          s = sc;
        }
        red[tid]=s; __syncthreads();
        for (int s2=128;s2>=1;s2>>=1){ if(j<s2) red[tid]=fmaxf(red[tid],red[tid+s2]); __syncthreads(); }
        const float m = red[half*256]; __syncthreads();
        const float e = (j<=st)? expf(s-m) : 0.f;
        if (j < T_) att_sm[half][j] = e;
        red[tid]=e; __syncthreads();
        for (int s2=128;s2>=1;s2>>=1){ if(j<s2) red[tid]+=red[tid+s2]; __syncthreads(); }
        const float inv = 1.f/red[half*256];
        if (j < HD_) {
          const __hip_bfloat16* vb = p.Vc + kvbase + j;
          float acc=0.f;
          for (int tt=0;tt<=st;++tt) acc += att_sm[half][tt]*__bfloat162float(vb[(size_t)tt*HD_]);
          p.o[b*D_ + hh*HD_ + j] = acc*inv;
        }
        __syncthreads();
      }
      gbar(p.sync, wg);

      //================= proj + residual + LN2, WGs 0..63 =================
      if (wg < B_) {
        const int b = wg, d = tid;
        const float* orow = p.o + b*D_;
        const float* wc = p.proj_w + l*(D_*D_) + d;
        float acc = p.proj_b[l*D_+d];
        #pragma unroll 8
        for (int k=0;k<D_;++k) acc += orow[k]*wc[k*D_];
        const float hv = p.h[b*D_+d] + acc;
        p.h[b*D_+d] = hv;
        red[tid]=hv; red2[tid]=hv*hv; __syncthreads();
        for (int s2=256;s2>=1;s2>>=1){ if(tid<s2){red[tid]+=red[tid+s2];red2[tid]+=red2[tid+s2];} __syncthreads(); }
        const float mu = red[0]*(1.f/D_);
        const float var = red2[0]*(1.f/D_)-mu*mu;
        const float rs = rsqrtf(var+1e-5f);
        p.hn2[b*D_+d] = (hv-mu)*rs*p.ln2_w[l*D_+d] + p.ln2_b[l*D_+d];
        __syncthreads();
      }
      gbar(p.sync, wg);

      //================= fc + gelu (exact erf), 256 virtual WGs =================
      for (int vv=0; vv<2; ++vv) {
        const int vw = wg + vv*NWG;
        const int b = vw>>2;
        const int n = (vw&3)*NT + tid;
        const float* hr = p.hn2 + b*D_;
        const float* wc = p.fc_w + l*(D_*D4_) + n;
        float acc = p.fc_b[l*D4_+n];
        #pragma unroll 8
        for (int k=0;k<D_;++k) acc += hr[k]*wc[k*D4_];
        p.g[b*D4_+n] = 0.5f*acc*(1.f+erff(acc*0.70710678118654752f));
      }
      gbar(p.sync, wg);

      //================= mproj + residual + (LN1next | lnf+head+ODE), WGs 0..63 =================
      if (wg < B_) {
        const int b = wg, d = tid;
        const float* grow = p.g + b*D4_;
        const float* wc = p.mproj_w + l*(D4_*D_) + d;
        float acc = p.mproj_b[l*D_+d];
        #pragma unroll 8
        for (int k=0;k<D4_;++k) acc += grow[k]*wc[k*D_];
        const float hv = p.h[b*D_+d] + acc;
        p.h[b*D_+d] = hv;
        red[tid]=hv; red2[tid]=hv*hv; __syncthreads();
        for (int s2=256;s2>=1;s2>>=1){ if(tid<s2){red[tid]+=red[tid+s2];red2[tid]+=red2[tid+s2];} __syncthreads(); }
        const float mu = red[0]*(1.f/D_);
        const float var = red2[0]*(1.f/D_)-mu*mu;
        const float rs = rsqrtf(var+1e-5f);
        __syncthreads();
        if (l < L_-1) {
          p.hn[b*D_+d] = (hv-mu)*rs*p.ln1_w[(l+1)*D_+d] + p.ln1_b[(l+1)*D_+d];
        } else {
          const float hf = (hv-mu)*rs*p.lnf_w[d] + p.lnf_b[d];
          red[tid]  = hf*p.head_w[d*2];
          red2[tid] = hf*p.head_w[d*2+1];
          __syncthreads();
          for (int s2=256;s2>=1;s2>>=1){ if(tid<s2){red[tid]+=red[tid+s2];red2[tid]+=red2[tid+s2];} __syncthreads(); }
          if (tid < 2) {
            const float un = ((tid==0)?red[0]:red2[0]) + p.head_b[tid];
            const float a  = p.data[b*4+tid];
            const float bb = p.data[b*4+2+tid];
            const float yv = p.y[b*2+tid];
            p.y[b*2+tid] = yv - a*yv + bb*un;   // y + (-a*y + b*u_next)
            p.u[b*2+tid] = un;
          }
          __syncthreads();
        }
      }
      gbar(p.sync, wg);
    } // layers
  } // steps
}

extern "C" void kernel_launch(void* const* d_in, const int* in_sizes, int n_in,
                              void* d_out, int out_size, void* d_ws, size_t ws_size,
                              hipStream_t stream) {
  P p;
  p.data  =(const float*)d_in[0];  p.r      =(const float*)d_in[1];
  p.y_d   =(const float*)d_in[2];  p.wte_w  =(const float*)d_in[3];
  p.wte_b =(const float*)d_in[4];  p.wpe    =(const float*)d_in[5];
  p.ln1_w =(const float*)d_in[6];  p.ln1_b  =(const float*)d_in[7];
  p.qkv_w =(const float*)d_in[8];  p.qkv_b  =(const float*)d_in[9];
  p.proj_w=(const float*)d_in[10]; p.proj_b =(const float*)d_in[11];
  p.ln2_w =(const float*)d_in[12]; p.ln2_b  =(const float*)d_in[13];
  p.fc_w  =(const float*)d_in[14]; p.fc_b   =(const float*)d_in[15];
  p.mproj_w=(const float*)d_in[16];p.mproj_b=(const float*)d_in[17];
  p.lnf_w =(const float*)d_in[18]; p.lnf_b  =(const float*)d_in[19];
  p.head_w=(const float*)d_in[20]; p.head_b =(const float*)d_in[21];
  p.out = (float*)d_out;

  char* w = (char*)d_ws;
  size_t off = 0;
  p.sync=(int*)(w+off);            off += 4096;
  p.y   =(float*)(w+off);          off += 512;
  p.u   =(float*)(w+off);          off += 512;
  p.h   =(float*)(w+off);          off += (size_t)B_*D_*4;
  p.hn  =(float*)(w+off);          off += (size_t)B_*D_*4;
  p.o   =(float*)(w+off);          off += (size_t)B_*D_*4;
  p.hn2 =(float*)(w+off);          off += (size_t)B_*D_*4;
  p.g   =(float*)(w+off);          off += (size_t)B_*D4_*4;
  p.Kc  =(__hip_bfloat16*)(w+off); off += (size_t)L_*B_*H_*T_*HD_*2;
  p.Vc  =(__hip_bfloat16*)(w+off); off += (size_t)L_*B_*H_*T_*HD_*2;

  fprintf(stderr, "[gptloop] ws_size=%zu need=%zu\n", ws_size, off);
  if (ws_size < off) return;  // leaves d_out poisoned -> clean failure, size visible in logs

  hipMemsetAsync(d_ws, 0, 4096, stream);  // zero barrier counters/generation
  hipLaunchKernelGGL(gptloop, dim3(NWG), dim3(NT), 0, stream, p);
}